// Round 1
// baseline (741.950 us; speedup 1.0000x reference)
//
#include <hip/hip_runtime.h>
#include <math.h>

// Problem constants (match reference)
#define NB 128          // graphs in batch
#define NL 1024         // links per graph
static constexpr float P_TX    = 10.0f;
static constexpr float P_NOISE = 6.2946e-14f;
static constexpr float INV_LN2 = 1.44269504088896340736f;

// ---------------------------------------------------------------------------
// Workspace layout: float rsum[NB]  (per-graph sum of rates)
// ---------------------------------------------------------------------------

__global__ void init_ws_kernel(float* __restrict__ rsum) {
    int t = threadIdx.x;
    if (t < NB) rsum[t] = 0.0f;
}

// One wave (64 lanes) per row (b,k). 256-thread blocks = 4 rows/block.
// 256 blocks per graph -> grid = NB * 256 = 32768 blocks.
__global__ __launch_bounds__(256) void rows_kernel(
        const float* __restrict__ prob,   // [NB*NL, 2]
        const float* __restrict__ H,      // [NB, NL, NL]
        float* __restrict__ rsum)         // [NB]
{
    __shared__ float py[NL];     // P_TX * y for this graph
    __shared__ float rvals[4];   // per-wave R results

    const int b    = blockIdx.x >> 8;          // 256 blocks per graph
    const int row0 = (blockIdx.x & 255) << 2;  // first link index k in block
    const int tid  = threadIdx.x;

    // Stage Py[b][:] into LDS (coalesced float2 loads of prob pairs).
    {
        const float2* p2 = (const float2*)prob + (size_t)b * NL;
        #pragma unroll
        for (int i = 0; i < 4; ++i) {
            int j = tid + 256 * i;
            py[j] = P_TX * p2[j].y;
        }
    }
    __syncthreads();

    const int wave = tid >> 6;
    const int lane = tid & 63;
    const int k    = row0 + wave;
    const float* __restrict__ Hrow = H + ((size_t)b * NL + k) * NL;

    // total[b,k] = sum_j H[b,k,j]^2 * Py[j]; 16 elements per lane via float4.
    float acc = 0.0f;
    #pragma unroll
    for (int it = 0; it < 4; ++it) {
        int j = it * 256 + lane * 4;
        float4 h4 = *(const float4*)(Hrow + j);
        float4 p4 = *(const float4*)(&py[j]);
        acc = fmaf(h4.x * h4.x, p4.x, acc);
        acc = fmaf(h4.y * h4.y, p4.y, acc);
        acc = fmaf(h4.z * h4.z, p4.z, acc);
        acc = fmaf(h4.w * h4.w, p4.w, acc);
    }

    // 64-lane wave reduction.
    #pragma unroll
    for (int off = 32; off >= 1; off >>= 1)
        acc += __shfl_down(acc, off, 64);

    if (lane == 0) {
        float hd     = Hrow[k];              // diagonal (L1-hot: wave just read it)
        float sig    = hd * hd * py[k];
        float interf = acc - sig + P_NOISE;
        float R      = log1pf(sig / interf) * INV_LN2;
        rvals[wave]  = R;
    }
    __syncthreads();

    if (tid == 0) {
        float s = rvals[0] + rvals[1] + rvals[2] + rvals[3];
        atomicAdd(&rsum[b], s);
    }
}

// loss = mean_b 1 / rsum[b]; single block of 128 threads.
__global__ void final_kernel(const float* __restrict__ rsum,
                             float* __restrict__ out)
{
    int t = threadIdx.x;             // 0..127
    float v = (1.0f / rsum[t]) * (1.0f / (float)NB);
    #pragma unroll
    for (int off = 32; off >= 1; off >>= 1)
        v += __shfl_down(v, off, 64);
    __shared__ float partial[2];
    if ((t & 63) == 0) partial[t >> 6] = v;
    __syncthreads();
    if (t == 0) out[0] = partial[0] + partial[1];
}

extern "C" void kernel_launch(void* const* d_in, const int* in_sizes, int n_in,
                              void* d_out, int out_size, void* d_ws, size_t ws_size,
                              hipStream_t stream) {
    const float* prob = (const float*)d_in[0];  // [NB*NL, 2]
    const float* H    = (const float*)d_in[1];  // [NB, NL, NL]
    float* out  = (float*)d_out;                // scalar
    float* rsum = (float*)d_ws;                 // NB floats

    init_ws_kernel<<<1, 128, 0, stream>>>(rsum);
    rows_kernel<<<NB * 256, 256, 0, stream>>>(prob, H, rsum);
    final_kernel<<<1, 128, 0, stream>>>(rsum, out);
}